// Round 4
// baseline (208.883 us; speedup 1.0000x reference)
//
#include <hip/hip_runtime.h>

// InstanceRecognizerReconstructor: multi-scale overlapping-window score
// scatter + coverage normalization.
//
// out[b,s,y,x] = (sum over windows (wy,wx) of scale SCALES[s] covering (y,x)
//                 of sim_s[b,wy,wx]) / (#covering windows)
//
// Separable transposed sum-pooling:
//   T[wy][x] = sum_wx sim[wy][wx]   (horizontal, <=K terms, K = scale/8)
//   out[y][x] = sum_wy T[wy][x]     (vertical,  <=K terms)
//   count(y,x) = ny(yb)*nx(xb)      (separable, yb=y>>3, xb=x>>3)
// Coverage predicate collapses to 0 <= wb - j < {XW,YW} for j in [0,K)
// because scale is a multiple of STRIDE=8.
//
// Phase-2 index algebra: with outF4 index i = tid + 256k, y = (tid>>5) + 8k,
// so yb == k exactly. ny is compile-time per unrolled k; c/xb/nx are
// loop-invariant per thread. Vertical sum kept as a running window:
// acc_k = acc_{k-1} + T[k] - T[k-K] (terms appear/drop at compile-time-known k).
//
// Output is write-once streaming (201 MB >> 32 MB L2): nontemporal stores
// (global_store_dwordx4 ... nt) avoid L2 allocation/eviction churn.
// NOTE: __builtin_nontemporal_store needs a NATIVE vector type, not HIP's
// float4 class -> use ext_vector_type(4) float (same 16B layout).

constexpr int HH = 96;
constexpr int WW = 128;

using vf4 = __attribute__((ext_vector_type(4))) float;

template <int SCALE, int YW, int XW>
__device__ __forceinline__ void run_scale(const float* __restrict__ sim,
                                          float* __restrict__ outPlane,
                                          float* __restrict__ s_sim,
                                          float* __restrict__ s_T, int b) {
  constexpr int K = SCALE / 8;
  constexpr int NSIM = YW * XW;
  const int tid = threadIdx.x;

  // Stage this batch's window scores (<=165 floats) into LDS.
  if (tid < NSIM) s_sim[tid] = sim[(size_t)b * NSIM + tid];
  __syncthreads();

  // ---- Phase 1: horizontal windowed sums T[wy][x] ----
  constexpr int P1 = YW * WW;
#pragma unroll
  for (int base = 0; base < P1; base += 256) {
    const int idx = base + tid;
    if ((base + 256 <= P1) || (idx < P1)) {   // tail check folds away when full
      const int wy = idx >> 7;                // window-grid row
      const int xb = (idx & (WW - 1)) >> 3;
      float t = 0.f;
#pragma unroll
      for (int j = 0; j < K; ++j) {
        const int wx = xb - j;
        t += (wx >= 0 && wx < XW) ? s_sim[wy * XW + wx] : 0.f;
      }
      s_T[idx] = t;
    }
  }
  __syncthreads();

  // ---- Phase 2: running vertical window + normalize; nt vf4 stores ----
  const int c  = tid & 31;                    // float4 chunk within row
  const int xb = c >> 1;                      // 8-px block (uniform over 4 elems)
  const int nx = min(xb, XW - 1) - max(0, xb - K + 1) + 1;
  const float fnx = (float)nx;
  const vf4* Tf4 = reinterpret_cast<const vf4*>(s_T) + c;
  vf4* outF4 = reinterpret_cast<vf4*>(outPlane) + tid;

  vf4 acc = (vf4)0.f;
#pragma unroll
  for (int k = 0; k < HH / 8; ++k) {          // yb == k
    if (k < YW) acc += Tf4[k * (WW / 4)];               // compile-time gate
    if (k - K >= 0 && k - K < YW) acc -= Tf4[(k - K) * (WW / 4)];
    const int ny = min(k, YW - 1) - max(0, k - K + 1) + 1;  // compile-time
    const float inv = __builtin_amdgcn_rcpf(fnx * (float)ny); // ~1ulp, ok
    const vf4 r = acc * inv;
    __builtin_nontemporal_store(r, outF4 + k * 256);  // 1 KB/wave, L2-bypass
  }
}

__global__ __launch_bounds__(256) void irr_score_kernel(
    const float* __restrict__ s0, const float* __restrict__ s1,
    const float* __restrict__ s2, const float* __restrict__ s3,
    float* __restrict__ out) {
  __shared__ float s_sim[176];        // worst case NSIM=165 (scale 16)
  __shared__ float s_T[11 * WW];      // worst case YW=11

  const int blk = blockIdx.x;
  const int b = blk >> 2;             // batch
  const int s = blk & 3;              // scale index (block-uniform)
  float* plane = out + (size_t)(b * 4 + s) * (HH * WW);
  switch (s) {
    case 0: run_scale<16, 11, 15>(s0, plane, s_sim, s_T, b); break;
    case 1: run_scale<24, 10, 14>(s1, plane, s_sim, s_T, b); break;
    case 2: run_scale<32,  9, 13>(s2, plane, s_sim, s_T, b); break;
    case 3: run_scale<48,  7, 11>(s3, plane, s_sim, s_T, b); break;
  }
}

extern "C" void kernel_launch(void* const* d_in, const int* in_sizes, int n_in,
                              void* d_out, int out_size, void* d_ws, size_t ws_size,
                              hipStream_t stream) {
  const float* s0 = (const float*)d_in[0];  // (B,1,11,15)
  const float* s1 = (const float*)d_in[1];  // (B,1,10,14)
  const float* s2 = (const float*)d_in[2];  // (B,1, 9,13)
  const float* s3 = (const float*)d_in[3];  // (B,1, 7,11)
  float* out = (float*)d_out;               // (B,4,96,128)

  const int B = in_sizes[0] / (11 * 15);
  dim3 grid(4 * B), block(256);
  irr_score_kernel<<<grid, block, 0, stream>>>(s0, s1, s2, s3, out);
}